// Round 4
// baseline (407.582 us; speedup 1.0000x reference)
//
#include <hip/hip_runtime.h>
#include <hip/hip_bf16.h>
#include <math.h>

namespace {

typedef unsigned long long u64;
typedef __attribute__((ext_vector_type(8))) short bf16x8;
typedef __attribute__((ext_vector_type(4))) float f32x4;

constexpr int KK = 5;
constexpr int K3 = 125;
constexpr int N0 = 16384, E0 = 262144;
constexpr int N1 = 4096,  E1 = 65536;
constexpr int N2 = 1024,  E2 = 16384;
constexpr int N3 = 256,   E3 = 4096;
constexpr int NV = 128;
constexpr int BB = 16;
constexpr int E_TOT = E0 + E1 + E2 + E3;     // 348160

// ---------------- workspace layout (float-slot offsets) ----------------
constexpr size_t A_PENC1 = 0;
constexpr size_t A_PENC2 = A_PENC1 + (size_t)N1 * 32;
constexpr size_t A_PENC3 = A_PENC2 + (size_t)N2 * 64;
constexpr size_t A_PENC4 = A_PENC3 + (size_t)N3 * 64;
constexpr size_t A_PENC_END = A_PENC4 + (size_t)NV * 128;
constexpr size_t PENC_TOTAL = A_PENC_END - A_PENC1;

constexpr size_t A_P1 = A_PENC_END;
constexpr size_t A_P2 = A_P1 + (size_t)N1 * 32;
constexpr size_t A_P3 = A_P2 + (size_t)N2 * 64;
constexpr size_t A_P4 = A_P3 + (size_t)N3 * 64;
constexpr size_t A_FC1 = A_P4 + (size_t)NV * 128;

constexpr size_t A_XB2 = A_FC1 + (size_t)BB * 256;        // bf16 buffers (2/ float)
constexpr size_t A_XB3 = A_XB2 + (size_t)N1 * 32 / 2;
constexpr size_t A_XB4 = A_XB3 + (size_t)N2 * 64 / 2;
constexpr size_t A_WT2 = A_XB4 + (size_t)N3 * 64 / 2;
constexpr size_t A_WT3 = A_WT2 + (size_t)K3 * 64 * 32 / 2;
constexpr size_t A_WT4 = A_WT3 + (size_t)K3 * 64 * 64 / 2;

constexpr size_t A_BAS0 = A_WT4 + (size_t)K3 * 128 * 64 / 2;
constexpr size_t A_KID0 = A_BAS0 + (size_t)E0 * 8;
constexpr size_t A_BAS1 = A_KID0 + (size_t)E0 * 2;
constexpr size_t A_KID1 = A_BAS1 + (size_t)E1 * 8;
constexpr size_t A_BAS2 = A_KID1 + (size_t)E1 * 2;
constexpr size_t A_KID2 = A_BAS2 + (size_t)E2 * 8;
constexpr size_t A_BAS3 = A_KID2 + (size_t)E2 * 2;
constexpr size_t A_KID3 = A_BAS3 + (size_t)E3 * 8;

constexpr size_t A_OFF0 = A_KID3 + (size_t)E3 * 2;
constexpr size_t A_OFF1 = A_OFF0 + (N0 + 4);
constexpr size_t A_OFF2 = A_OFF1 + (N1 + 4);
constexpr size_t A_OFF3 = A_OFF2 + (N2 + 4);
constexpr size_t A_CUR0 = A_OFF3 + (N3 + 4);
constexpr size_t A_CUR1 = A_CUR0 + N0;
constexpr size_t A_CUR2 = A_CUR1 + N1;
constexpr size_t A_CUR3 = A_CUR2 + N2;
constexpr size_t A_CUR_END = A_CUR3 + N3;
constexpr size_t CUR_TOTAL = A_CUR_END - A_CUR0;          // 21760
constexpr size_t A_EIX0 = A_CUR_END;
constexpr size_t A_EIX1 = A_EIX0 + E0;
constexpr size_t A_EIX2 = A_EIX1 + E1;
constexpr size_t A_EIX3 = A_EIX2 + E2;
constexpr size_t A_Y = A_EIX3 + E3;
constexpr size_t A_END = A_Y + (size_t)N1 * (K3 * 64) / 2; // ~87 MB total

// ---------------- helpers ----------------
__device__ __forceinline__ float eluf(float x) { return x > 0.f ? x : expm1f(x); }

__device__ __forceinline__ unsigned enc_f(float x) {
    unsigned u = __float_as_uint(x);
    return (u & 0x80000000u) ? ~u : (u | 0x80000000u);
}
__device__ __forceinline__ float dec_f(unsigned u) {
    u = (u & 0x80000000u) ? (u & 0x7fffffffu) : ~u;
    return __uint_as_float(u);
}
__device__ __forceinline__ float bf2f(unsigned short u) {
    return __uint_as_float((unsigned)u << 16);
}
__device__ __forceinline__ unsigned short f2bf(float v) {
    __hip_bfloat16 h = __float2bfloat16(v);
    return *reinterpret_cast<unsigned short*>(&h);
}

__device__ __forceinline__ void decode_edge(const float* __restrict__ pseudo, int e,
                                            float bas[8], int kid[8]) {
    float v0 = pseudo[e * 3 + 0] * (KK - 1);
    float v1 = pseudo[e * 3 + 1] * (KK - 1);
    float v2 = pseudo[e * 3 + 2] * (KK - 1);
    float f0 = fminf(fmaxf(floorf(v0), 0.f), (float)(KK - 2));
    float f1 = fminf(fmaxf(floorf(v1), 0.f), (float)(KK - 2));
    float f2 = fminf(fmaxf(floorf(v2), 0.f), (float)(KK - 2));
    int lo0 = (int)f0, lo1 = (int)f1, lo2 = (int)f2;
    float fr0 = v0 - f0, fr1 = v1 - f1, fr2 = v2 - f2;
#pragma unroll
    for (int c = 0; c < 8; ++c) {
        int b0 = c & 1, b1 = (c >> 1) & 1, b2 = (c >> 2) & 1;
        kid[c] = (lo0 + b0) + (lo1 + b1) * KK + (lo2 + b2) * KK * KK;
        bas[c] = (b0 ? fr0 : 1.f - fr0) * (b1 ? fr1 : 1.f - fr1) * (b2 ? fr2 : 1.f - fr2);
    }
}

__global__ void init_enc(unsigned* __restrict__ p, int n) {
    int g = blockIdx.x * blockDim.x + threadIdx.x;
    if (g < n) p[g] = 0x007FFFFFu;   // enc(-inf)
}

// ---------------- all-layer decode: pseudo -> bas/kid tables ----------------
__global__ void decode_all(const float* __restrict__ ps0, const float* __restrict__ ps1,
                           const float* __restrict__ ps2, const float* __restrict__ ps3,
                           float* __restrict__ bas0, u64* __restrict__ kid0,
                           float* __restrict__ bas1, u64* __restrict__ kid1,
                           float* __restrict__ bas2, u64* __restrict__ kid2,
                           float* __restrict__ bas3, u64* __restrict__ kid3) {
    int g = blockIdx.x * blockDim.x + threadIdx.x;
    const float* ps; float* bas; u64* kid; int e;
    if (g < E0)                { ps = ps0; bas = bas0; kid = kid0; e = g; }
    else if (g < E0 + E1)      { ps = ps1; bas = bas1; kid = kid1; e = g - E0; }
    else if (g < E0 + E1 + E2) { ps = ps2; bas = bas2; kid = kid2; e = g - E0 - E1; }
    else if (g < E_TOT)        { ps = ps3; bas = bas3; kid = kid3; e = g - E0 - E1 - E2; }
    else return;
    float b[8]; int k[8];
    decode_edge(ps, e, b, k);
    *(float4*)(bas + (size_t)e * 8)     = make_float4(b[0], b[1], b[2], b[3]);
    *(float4*)(bas + (size_t)e * 8 + 4) = make_float4(b[4], b[5], b[6], b[7]);
    u64 p = 0;
#pragma unroll
    for (int c = 0; c < 8; ++c) p |= (u64)(unsigned)k[c] << (8 * c);
    kid[e] = p;
}

// ---------------- CSR build: hist -> scan -> scatter ----------------
__global__ void csr_hist(const int* __restrict__ d0, const int* __restrict__ d1,
                         const int* __restrict__ d2, const int* __restrict__ d3,
                         int* __restrict__ c0, int* __restrict__ c1,
                         int* __restrict__ c2, int* __restrict__ c3) {
    int g = blockIdx.x * blockDim.x + threadIdx.x;
    if (g < E0)                atomicAdd(&c0[d0[g]], 1);
    else if (g < E0 + E1)      atomicAdd(&c1[d1[g - E0]], 1);
    else if (g < E0 + E1 + E2) atomicAdd(&c2[d2[g - E0 - E1]], 1);
    else if (g < E_TOT)        atomicAdd(&c3[d3[g - E0 - E1 - E2]], 1);
}

__global__ void csr_scan(int* __restrict__ c0, int* __restrict__ o0,
                         int* __restrict__ c1, int* __restrict__ o1,
                         int* __restrict__ c2, int* __restrict__ o2,
                         int* __restrict__ c3, int* __restrict__ o3) {
    __shared__ int ls[1024];
    int* cur; int* off; int N;
    switch (blockIdx.x) {
        case 0:  cur = c0; off = o0; N = N0; break;
        case 1:  cur = c1; off = o1; N = N1; break;
        case 2:  cur = c2; off = o2; N = N2; break;
        default: cur = c3; off = o3; N = N3; break;
    }
    int t = threadIdx.x;
    int chunk = (N + 1023) >> 10;
    int b0 = t * chunk;
    int b1 = min(b0 + chunk, N);
    int s = 0;
    for (int i = b0; i < b1; ++i) s += cur[i];
    ls[t] = s;
    __syncthreads();
    for (int d = 1; d < 1024; d <<= 1) {
        int v = (t >= d) ? ls[t - d] : 0;
        __syncthreads();
        ls[t] += v;
        __syncthreads();
    }
    int run = (t == 0) ? 0 : ls[t - 1];
    for (int i = b0; i < b1; ++i) {
        int c = cur[i];
        off[i] = run;
        cur[i] = run;   // cursor for scatter
        run += c;
    }
    if (t == 1023) off[N] = run;
}

__global__ void csr_scatter(const int* __restrict__ d0, const int* __restrict__ d1,
                            const int* __restrict__ d2, const int* __restrict__ d3,
                            int* __restrict__ c0, int* __restrict__ c1,
                            int* __restrict__ c2, int* __restrict__ c3,
                            int* __restrict__ x0, int* __restrict__ x1,
                            int* __restrict__ x2, int* __restrict__ x3) {
    int g = blockIdx.x * blockDim.x + threadIdx.x;
    if (g < E0)                { int p = atomicAdd(&c0[d0[g]], 1);            x0[p] = g; }
    else if (g < E0 + E1)      { int e = g - E0;        int p = atomicAdd(&c1[d1[e]], 1); x1[p] = e; }
    else if (g < E0 + E1 + E2) { int e = g - E0 - E1;   int p = atomicAdd(&c2[d2[e]], 1); x2[p] = e; }
    else if (g < E_TOT)        { int e = g - E0 - E1 - E2; int p = atomicAdd(&c3[d3[e]], 1); x3[p] = e; }
}

// ---------------- W transpose+cast via LDS: W[k][i][o] -> wt[(k*OUT+o)][i] bf16 ----
__global__ void conv_wt(const float* __restrict__ W2, const float* __restrict__ W3,
                        const float* __restrict__ W4,
                        unsigned short* __restrict__ wt2, unsigned short* __restrict__ wt3,
                        unsigned short* __restrict__ wt4) {
    __shared__ float st[64 * 129];
    int kb = blockIdx.x;
    const float* W; unsigned short* wt; int IN, OUT, k;
    if (kb < K3)          { W = W2; wt = wt2; IN = 32; OUT = 64;  k = kb; }
    else if (kb < 2 * K3) { W = W3; wt = wt3; IN = 64; OUT = 64;  k = kb - K3; }
    else                  { W = W4; wt = wt4; IN = 64; OUT = 128; k = kb - 2 * K3; }
    int tid = threadIdx.x;
    int tot = IN * OUT;
    const float* Wk = W + (size_t)k * tot;
    for (int idx = tid; idx < tot; idx += 256) {
        int i = idx / OUT, o = idx % OUT;
        st[i * (OUT + 1) + o] = Wk[idx];
    }
    __syncthreads();
    unsigned short* wk = wt + (size_t)k * tot;
    for (int idx = tid; idx < tot; idx += 256) {
        int o = idx / IN, i = idx % IN;
        wk[idx] = f2bf(st[i * (OUT + 1) + o]);
    }
}

// ---------------- layer 1: wave-per-node (half-wave), W1 in LDS, atomic-free agg ----
__global__ __launch_bounds__(256) void l1_agg(const float* __restrict__ x0,
                                              const float* __restrict__ bas,
                                              const u64* __restrict__ kid,
                                              const int* __restrict__ src,
                                              const int* __restrict__ off,
                                              const int* __restrict__ eidx,
                                              const float* __restrict__ W1,
                                              const float* __restrict__ root1,
                                              const float* __restrict__ b1,
                                              const int* __restrict__ cl,
                                              unsigned* __restrict__ penc) {
    __shared__ float wlds[K3 * 32];
    int tid = threadIdx.x;
    for (int i = tid; i < K3 * 32; i += 256) wlds[i] = W1[i];
    __syncthreads();
    int o = tid & 31;
    int nsub = tid >> 5;                  // 0..7
    int n = blockIdx.x * 8 + nsub;
    int s0 = off[n], s1 = off[n + 1];
    float acc = 0.f;
    for (int j = s0; j < s1; ++j) {
        int e = eidx[j];
        float4 q0 = *(const float4*)(bas + (size_t)e * 8);
        float4 q1 = *(const float4*)(bas + (size_t)e * 8 + 4);
        u64 k8 = kid[e];
        float xv = x0[src[e]];
        float m;
        m  = q0.x * wlds[((int)( k8        & 255u)) * 32 + o];
        m += q0.y * wlds[((int)((k8 >>  8) & 255u)) * 32 + o];
        m += q0.z * wlds[((int)((k8 >> 16) & 255u)) * 32 + o];
        m += q0.w * wlds[((int)((k8 >> 24) & 255u)) * 32 + o];
        m += q1.x * wlds[((int)((k8 >> 32) & 255u)) * 32 + o];
        m += q1.y * wlds[((int)((k8 >> 40) & 255u)) * 32 + o];
        m += q1.z * wlds[((int)((k8 >> 48) & 255u)) * 32 + o];
        m += q1.w * wlds[((int)((k8 >> 56) & 255u)) * 32 + o];
        acc = fmaf(xv, m, acc);
    }
    float dg = fmaxf((float)(s1 - s0), 1.f);
    float val = acc / dg + x0[n] * root1[o] + b1[o];
    val = eluf(val);
    atomicMax(&penc[(size_t)cl[n] * 32 + o], enc_f(val));
}

// ---------------- pool finalize (+ optional bf16 cast for next layer) ----------------
template <bool WBF>
__global__ void pool_fin(const unsigned* __restrict__ penc, float* __restrict__ P,
                         unsigned short* __restrict__ xb, int M) {
    int g = blockIdx.x * blockDim.x + threadIdx.x;
    if (g >= M) return;
    float v = dec_f(penc[g]);
    v = isfinite(v) ? v : 0.f;
    P[g] = v;
    if (WBF) xb[g] = f2bf(v);
}

// ---------------- MFMA y = x @ W  (y[n][ko] bf16) ----------------
template <int IN>
__global__ __launch_bounds__(256) void gemm_y_mfma(const unsigned short* __restrict__ xb,
                                                   const unsigned short* __restrict__ wt,
                                                   unsigned short* __restrict__ y,
                                                   int N, int KO) {
    int wid = (blockIdx.x * 256 + threadIdx.x) >> 6;
    int lane = threadIdx.x & 63;
    int nTiles = N >> 4;
    int n0 = (wid % nTiles) << 4;
    int ko0 = (wid / nTiles) << 6;
    int l15 = lane & 15;
    int kk = (lane >> 4) << 3;

    f32x4 acc[4];
#pragma unroll
    for (int t = 0; t < 4; ++t) acc[t] = (f32x4){0.f, 0.f, 0.f, 0.f};

#pragma unroll
    for (int s = 0; s < IN / 32; ++s) {
        bf16x8 bfrag = *(const bf16x8*)(xb + (size_t)(n0 + l15) * IN + s * 32 + kk);
#pragma unroll
        for (int t = 0; t < 4; ++t) {
            bf16x8 afrag = *(const bf16x8*)(wt + (size_t)(ko0 + t * 16 + l15) * IN + s * 32 + kk);
            acc[t] = __builtin_amdgcn_mfma_f32_16x16x32_bf16(afrag, bfrag, acc[t], 0, 0, 0);
        }
    }
    int rbase = (lane >> 4) << 2;
#pragma unroll
    for (int t = 0; t < 4; ++t) {
        ushort4 sv;
        sv.x = f2bf(acc[t][0]);
        sv.y = f2bf(acc[t][1]);
        sv.z = f2bf(acc[t][2]);
        sv.w = f2bf(acc[t][3]);
        *(ushort4*)(y + (size_t)(n0 + l15) * KO + ko0 + t * 16 + rbase) = sv;
    }
}

// ---------------- layers 2-4: wave-per-node gather+agg+finish+pool, atomic-free ----
template <int IN, int OUT>
__global__ __launch_bounds__(256) void gather_agg(const unsigned short* __restrict__ y,
                                                  const float* __restrict__ bas,
                                                  const u64* __restrict__ kid,
                                                  const int* __restrict__ src,
                                                  const int* __restrict__ off,
                                                  const int* __restrict__ eidx,
                                                  const float* __restrict__ P,
                                                  const float* __restrict__ root,
                                                  const float* __restrict__ bias,
                                                  const int* __restrict__ cl,
                                                  unsigned* __restrict__ penc) {
    constexpr int KO = K3 * OUT;
    constexpr int WPT = OUT / 64;
    int lane = threadIdx.x & 63;
    int wv = threadIdx.x >> 6;
    int n = blockIdx.x * 4 + wv;
    int s0 = off[n], s1 = off[n + 1];
    float acc[WPT];
#pragma unroll
    for (int w = 0; w < WPT; ++w) acc[w] = 0.f;
    for (int j = s0; j < s1; ++j) {
        int e = eidx[j];
        float4 q0 = *(const float4*)(bas + (size_t)e * 8);
        float4 q1 = *(const float4*)(bas + (size_t)e * 8 + 4);
        u64 k8 = kid[e];
        const unsigned short* yp = y + (size_t)src[e] * KO;
        float b[8] = {q0.x, q0.y, q0.z, q0.w, q1.x, q1.y, q1.z, q1.w};
#pragma unroll
        for (int c = 0; c < 8; ++c) {
            int kc = (int)((k8 >> (8 * c)) & 255u);
            const unsigned short* cp = yp + (size_t)kc * OUT + lane;
            acc[0] = fmaf(b[c], bf2f(cp[0]), acc[0]);
            if (WPT == 2) acc[1] = fmaf(b[c], bf2f(cp[64]), acc[1]);
        }
    }
    float dg = fmaxf((float)(s1 - s0), 1.f);
#pragma unroll
    for (int w = 0; w < WPT; ++w) {
        int o = lane + 64 * w;
        float r = 0.f;
        for (int i = 0; i < IN; ++i)
            r = fmaf(P[(size_t)n * IN + i], root[(size_t)i * OUT + o], r);
        float val = acc[w] / dg + r + bias[o];
        val = eluf(val);
        atomicMax(&penc[(size_t)cl[n] * OUT + o], enc_f(val));
    }
}

// ---------------- FC head ----------------
__global__ void fc1_kernel(const float* __restrict__ xin,
                           const float* __restrict__ w,
                           const float* __restrict__ b,
                           float* __restrict__ out) {
    __shared__ float part[4][64];
    int bq = blockIdx.x >> 2, q = blockIdx.x & 3;
    int t = threadIdx.x;
    int ol = t & 63, sub = t >> 6;
    int p = q * 64 + ol;
    const float* xr = xin + (size_t)bq * 1024 + sub * 256;
    const float* wp = w + (size_t)(sub * 256) * 256 + p;
    float acc = 0.f;
    for (int j = 0; j < 256; ++j)
        acc = fmaf(xr[j], wp[(size_t)j * 256], acc);
    part[sub][ol] = acc;
    __syncthreads();
    if (sub == 0) {
        float v = part[0][ol] + part[1][ol] + part[2][ol] + part[3][ol] + b[p];
        out[(size_t)bq * 256 + p] = eluf(v);
    }
}

__global__ void fc2_ls_kernel(const float* __restrict__ xin,
                              const float* __restrict__ w,
                              const float* __restrict__ b,
                              float* __restrict__ out) {
    __shared__ float l[10];
    __shared__ float red[2];
    int bq = blockIdx.x;
    int t = threadIdx.x;        // 64
    if (t < 10) {
        const float* xr = xin + (size_t)bq * 256;
        float acc = b[t];
        for (int q = 0; q < 256; ++q)
            acc = fmaf(xr[q], w[(size_t)q * 10 + t], acc);
        l[t] = acc;
    }
    __syncthreads();
    if (t == 0) {
        float m = l[0];
        for (int i = 1; i < 10; ++i) m = fmaxf(m, l[i]);
        float s = 0.f;
        for (int i = 0; i < 10; ++i) s += expf(l[i] - m);
        red[0] = m;
        red[1] = logf(s);
    }
    __syncthreads();
    if (t < 10) out[(size_t)bq * 10 + t] = l[t] - red[0] - red[1];
}

inline unsigned blk(long long t) { return (unsigned)((t + 255) / 256); }

} // namespace

extern "C" void kernel_launch(void* const* d_in, const int* in_sizes, int n_in,
                              void* d_out, int out_size, void* d_ws, size_t ws_size,
                              hipStream_t stream) {
    const float* x0    = (const float*)d_in[0];
    const float* ps0   = (const float*)d_in[1];
    const float* ps1   = (const float*)d_in[2];
    const float* ps2   = (const float*)d_in[3];
    const float* ps3   = (const float*)d_in[4];
    const float* W1    = (const float*)d_in[5];
    const float* root1 = (const float*)d_in[6];
    const float* b1    = (const float*)d_in[7];
    const float* W2    = (const float*)d_in[8];
    const float* root2 = (const float*)d_in[9];
    const float* b2    = (const float*)d_in[10];
    const float* W3    = (const float*)d_in[11];
    const float* root3 = (const float*)d_in[12];
    const float* b3    = (const float*)d_in[13];
    const float* W4    = (const float*)d_in[14];
    const float* root4 = (const float*)d_in[15];
    const float* b4    = (const float*)d_in[16];
    const float* fc1w  = (const float*)d_in[17];
    const float* fc1b  = (const float*)d_in[18];
    const float* fc2w  = (const float*)d_in[19];
    const float* fc2b  = (const float*)d_in[20];
    const int* src0 = (const int*)d_in[21];
    const int* dst0 = (const int*)d_in[22];
    const int* src1 = (const int*)d_in[23];
    const int* dst1 = (const int*)d_in[24];
    const int* src2 = (const int*)d_in[25];
    const int* dst2 = (const int*)d_in[26];
    const int* src3 = (const int*)d_in[27];
    const int* dst3 = (const int*)d_in[28];
    const int* cl0  = (const int*)d_in[29];
    const int* cl1  = (const int*)d_in[30];
    const int* cl2  = (const int*)d_in[31];
    const int* cl3  = (const int*)d_in[32];

    float* ws = (float*)d_ws;
    float* out = (float*)d_out;

    unsigned* penc1 = (unsigned*)(ws + A_PENC1);
    unsigned* penc2 = (unsigned*)(ws + A_PENC2);
    unsigned* penc3 = (unsigned*)(ws + A_PENC3);
    unsigned* penc4 = (unsigned*)(ws + A_PENC4);
    float* P1 = ws + A_P1;  float* P2 = ws + A_P2;
    float* P3 = ws + A_P3;  float* P4 = ws + A_P4;
    float* fc1o = ws + A_FC1;
    unsigned short* xb2 = (unsigned short*)(ws + A_XB2);
    unsigned short* xb3 = (unsigned short*)(ws + A_XB3);
    unsigned short* xb4 = (unsigned short*)(ws + A_XB4);
    unsigned short* wt2 = (unsigned short*)(ws + A_WT2);
    unsigned short* wt3 = (unsigned short*)(ws + A_WT3);
    unsigned short* wt4 = (unsigned short*)(ws + A_WT4);
    float* bas0 = ws + A_BAS0;  u64* kid0 = (u64*)(ws + A_KID0);
    float* bas1 = ws + A_BAS1;  u64* kid1 = (u64*)(ws + A_KID1);
    float* bas2 = ws + A_BAS2;  u64* kid2 = (u64*)(ws + A_KID2);
    float* bas3 = ws + A_BAS3;  u64* kid3 = (u64*)(ws + A_KID3);
    int* off0 = (int*)(ws + A_OFF0);  int* cur0 = (int*)(ws + A_CUR0);  int* eix0 = (int*)(ws + A_EIX0);
    int* off1 = (int*)(ws + A_OFF1);  int* cur1 = (int*)(ws + A_CUR1);  int* eix1 = (int*)(ws + A_EIX1);
    int* off2 = (int*)(ws + A_OFF2);  int* cur2 = (int*)(ws + A_CUR2);  int* eix2 = (int*)(ws + A_EIX2);
    int* off3 = (int*)(ws + A_OFF3);  int* cur3 = (int*)(ws + A_CUR3);  int* eix3 = (int*)(ws + A_EIX3);
    unsigned short* yb = (unsigned short*)(ws + A_Y);

    // ---- init ----
    hipMemsetAsync(ws + A_CUR0, 0, CUR_TOTAL * sizeof(int), stream);
    init_enc<<<blk(PENC_TOTAL), 256, 0, stream>>>(penc1, (int)PENC_TOTAL);

    // ---- prologue: decode all bases, build all CSRs, transpose all Ws ----
    decode_all<<<blk(E_TOT), 256, 0, stream>>>(ps0, ps1, ps2, ps3,
                                               bas0, kid0, bas1, kid1, bas2, kid2, bas3, kid3);
    csr_hist<<<blk(E_TOT), 256, 0, stream>>>(dst0, dst1, dst2, dst3, cur0, cur1, cur2, cur3);
    csr_scan<<<4, 1024, 0, stream>>>(cur0, off0, cur1, off1, cur2, off2, cur3, off3);
    csr_scatter<<<blk(E_TOT), 256, 0, stream>>>(dst0, dst1, dst2, dst3,
                                                cur0, cur1, cur2, cur3, eix0, eix1, eix2, eix3);
    conv_wt<<<3 * K3, 256, 0, stream>>>(W2, W3, W4, wt2, wt3, wt4);

    // ---- layer 1: conv(1->32) on N0, pool -> N1 ----
    l1_agg<<<N0 / 8, 256, 0, stream>>>(x0, bas0, kid0, src0, off0, eix0, W1, root1, b1, cl0, penc1);
    pool_fin<true><<<blk((long long)N1 * 32), 256, 0, stream>>>(penc1, P1, xb2, N1 * 32);

    // ---- layer 2: conv(32->64) on N1, pool -> N2 ----
    gemm_y_mfma<32><<<(N1 / 16) * (K3 * 64 / 64) / 4, 256, 0, stream>>>(xb2, wt2, yb, N1, K3 * 64);
    gather_agg<32, 64><<<N1 / 4, 256, 0, stream>>>(yb, bas1, kid1, src1, off1, eix1,
                                                   P1, root2, b2, cl1, penc2);
    pool_fin<true><<<blk((long long)N2 * 64), 256, 0, stream>>>(penc2, P2, xb3, N2 * 64);

    // ---- layer 3: conv(64->64) on N2, pool -> N3 ----
    gemm_y_mfma<64><<<(N2 / 16) * (K3 * 64 / 64) / 4, 256, 0, stream>>>(xb3, wt3, yb, N2, K3 * 64);
    gather_agg<64, 64><<<N2 / 4, 256, 0, stream>>>(yb, bas2, kid2, src2, off2, eix2,
                                                   P2, root3, b3, cl2, penc3);
    pool_fin<true><<<blk((long long)N3 * 64), 256, 0, stream>>>(penc3, P3, xb4, N3 * 64);

    // ---- layer 4: conv(64->128) on N3, pool -> V=128 ----
    gemm_y_mfma<64><<<(N3 / 16) * (K3 * 128 / 64) / 4, 256, 0, stream>>>(xb4, wt4, yb, N3, K3 * 128);
    gather_agg<64, 128><<<N3 / 4, 256, 0, stream>>>(yb, bas3, kid3, src3, off3, eix3,
                                                    P3, root4, b4, cl3, penc4);
    pool_fin<false><<<blk((long long)NV * 128), 256, 0, stream>>>(penc4, P4, nullptr, NV * 128);

    // ---- FC head ----
    fc1_kernel<<<64, 256, 0, stream>>>(P4, fc1w, fc1b, fc1o);
    fc2_ls_kernel<<<16, 64, 0, stream>>>(fc1o, fc2w, fc2b, out);
}

// Round 5
// 405.967 us; speedup vs baseline: 1.0040x; 1.0040x over previous
//
#include <hip/hip_runtime.h>
#include <hip/hip_bf16.h>
#include <math.h>

namespace {

typedef unsigned long long u64;
typedef __attribute__((ext_vector_type(8))) short bf16x8;
typedef __attribute__((ext_vector_type(4))) float f32x4;

constexpr int KK = 5;
constexpr int K3 = 125;
constexpr int N0 = 16384, E0 = 262144;
constexpr int N1 = 4096,  E1 = 65536;
constexpr int N2 = 1024,  E2 = 16384;
constexpr int N3 = 256,   E3 = 4096;
constexpr int NV = 128;
constexpr int E_TOT = E0 + E1 + E2 + E3;     // 348160
constexpr unsigned ENC_NEG_INF = 0x007FFFFFu;

// ---------------- workspace layout (float-slot offsets) ----------------
constexpr size_t A_PENC1 = 0;                              // N1*32
constexpr size_t A_PENC2 = A_PENC1 + (size_t)N1 * 32;      // N2*64
constexpr size_t A_PENC3 = A_PENC2 + (size_t)N2 * 64;      // N3*64
constexpr size_t A_PENC4 = A_PENC3 + (size_t)N3 * 64;      // NV*128
constexpr size_t A_PENC_END = A_PENC4 + (size_t)NV * 128;
constexpr size_t PENC_TOTAL = A_PENC_END;                  // 229376

constexpr size_t A_WT2 = A_PENC_END;                       // bf16: K3*64*32
constexpr size_t A_WT3 = A_WT2 + (size_t)K3 * 64 * 32 / 2;
constexpr size_t A_WT4 = A_WT3 + (size_t)K3 * 64 * 64 / 2;

constexpr size_t A_BAS0 = A_WT4 + (size_t)K3 * 128 * 64 / 2;
constexpr size_t A_KID0 = A_BAS0 + (size_t)E0 * 8;
constexpr size_t A_BAS1 = A_KID0 + (size_t)E0 * 2;
constexpr size_t A_KID1 = A_BAS1 + (size_t)E1 * 8;
constexpr size_t A_BAS2 = A_KID1 + (size_t)E1 * 2;
constexpr size_t A_KID2 = A_BAS2 + (size_t)E2 * 8;
constexpr size_t A_BAS3 = A_KID2 + (size_t)E2 * 2;
constexpr size_t A_KID3 = A_BAS3 + (size_t)E3 * 8;

constexpr size_t A_OFF0 = A_KID3 + (size_t)E3 * 2;
constexpr size_t A_OFF1 = A_OFF0 + (N0 + 4);
constexpr size_t A_OFF2 = A_OFF1 + (N1 + 4);
constexpr size_t A_OFF3 = A_OFF2 + (N2 + 4);
constexpr size_t A_CUR0 = A_OFF3 + (N3 + 4);
constexpr size_t A_CUR1 = A_CUR0 + N0;
constexpr size_t A_CUR2 = A_CUR1 + N1;
constexpr size_t A_CUR3 = A_CUR2 + N2;
constexpr size_t A_CUR_END = A_CUR3 + N3;
constexpr size_t CUR_TOTAL = A_CUR_END - A_CUR0;           // 21760
constexpr size_t A_EIX0 = A_CUR_END;
constexpr size_t A_EIX1 = A_EIX0 + E0;
constexpr size_t A_EIX2 = A_EIX1 + E1;
constexpr size_t A_EIX3 = A_EIX2 + E2;
constexpr size_t A_Y = A_EIX3 + E3;                        // bf16, max N1*8000

// ---------------- helpers ----------------
__device__ __forceinline__ float eluf(float x) { return x > 0.f ? x : expm1f(x); }

__device__ __forceinline__ unsigned enc_f(float x) {
    unsigned u = __float_as_uint(x);
    return (u & 0x80000000u) ? ~u : (u | 0x80000000u);
}
__device__ __forceinline__ float dec_fin(unsigned u) {   // decode + (-inf -> 0)
    u = (u & 0x80000000u) ? (u & 0x7fffffffu) : ~u;
    float v = __uint_as_float(u);
    return isfinite(v) ? v : 0.f;
}
__device__ __forceinline__ float bf2f(unsigned short u) {
    return __uint_as_float((unsigned)u << 16);
}
__device__ __forceinline__ unsigned short f2bf(float v) {
    __hip_bfloat16 h = __float2bfloat16(v);
    return *reinterpret_cast<unsigned short*>(&h);
}

__device__ __forceinline__ void decode_edge(const float* __restrict__ pseudo, int e,
                                            float bas[8], int kid[8]) {
    float v0 = pseudo[e * 3 + 0] * (KK - 1);
    float v1 = pseudo[e * 3 + 1] * (KK - 1);
    float v2 = pseudo[e * 3 + 2] * (KK - 1);
    float f0 = fminf(fmaxf(floorf(v0), 0.f), (float)(KK - 2));
    float f1 = fminf(fmaxf(floorf(v1), 0.f), (float)(KK - 2));
    float f2 = fminf(fmaxf(floorf(v2), 0.f), (float)(KK - 2));
    int lo0 = (int)f0, lo1 = (int)f1, lo2 = (int)f2;
    float fr0 = v0 - f0, fr1 = v1 - f1, fr2 = v2 - f2;
#pragma unroll
    for (int c = 0; c < 8; ++c) {
        int b0 = c & 1, b1 = (c >> 1) & 1, b2 = (c >> 2) & 1;
        kid[c] = (lo0 + b0) + (lo1 + b1) * KK + (lo2 + b2) * KK * KK;
        bas[c] = (b0 ? fr0 : 1.f - fr0) * (b1 ? fr1 : 1.f - fr1) * (b2 ? fr2 : 1.f - fr2);
    }
}

// ---------------- P1: decode all bases + init penc + zero cursors ----------------
__global__ void prologue1(const float* __restrict__ ps0, const float* __restrict__ ps1,
                          const float* __restrict__ ps2, const float* __restrict__ ps3,
                          float* __restrict__ ws) {
    int g = blockIdx.x * blockDim.x + threadIdx.x;
    if (g < (int)PENC_TOTAL) ((unsigned*)(ws + A_PENC1))[g] = ENC_NEG_INF;
    if (g < (int)CUR_TOTAL) ((int*)(ws + A_CUR0))[g] = 0;
    if (g >= E_TOT) return;
    const float* ps; float* bas; u64* kid; int e;
    if (g < E0)                { ps = ps0; bas = ws + A_BAS0; kid = (u64*)(ws + A_KID0); e = g; }
    else if (g < E0 + E1)      { ps = ps1; bas = ws + A_BAS1; kid = (u64*)(ws + A_KID1); e = g - E0; }
    else if (g < E0 + E1 + E2) { ps = ps2; bas = ws + A_BAS2; kid = (u64*)(ws + A_KID2); e = g - E0 - E1; }
    else                       { ps = ps3; bas = ws + A_BAS3; kid = (u64*)(ws + A_KID3); e = g - E0 - E1 - E2; }
    float b[8]; int k[8];
    decode_edge(ps, e, b, k);
    *(float4*)(bas + (size_t)e * 8)     = make_float4(b[0], b[1], b[2], b[3]);
    *(float4*)(bas + (size_t)e * 8 + 4) = make_float4(b[4], b[5], b[6], b[7]);
    u64 p = 0;
#pragma unroll
    for (int c = 0; c < 8; ++c) p |= (u64)(unsigned)k[c] << (8 * c);
    kid[e] = p;
}

// ---------------- P2: histogram of dst ----------------
__global__ void csr_hist(const int* __restrict__ d0, const int* __restrict__ d1,
                         const int* __restrict__ d2, const int* __restrict__ d3,
                         float* __restrict__ ws) {
    int g = blockIdx.x * blockDim.x + threadIdx.x;
    if (g < E0)                atomicAdd((int*)(ws + A_CUR0) + d0[g], 1);
    else if (g < E0 + E1)      atomicAdd((int*)(ws + A_CUR1) + d1[g - E0], 1);
    else if (g < E0 + E1 + E2) atomicAdd((int*)(ws + A_CUR2) + d2[g - E0 - E1], 1);
    else if (g < E_TOT)        atomicAdd((int*)(ws + A_CUR3) + d3[g - E0 - E1 - E2], 1);
}

// ---------------- P3: exclusive scan per layer (4 blocks) ----------------
__global__ void csr_scan(float* __restrict__ ws) {
    __shared__ int ls[1024];
    int* cur; int* off; int N;
    switch (blockIdx.x) {
        case 0:  cur = (int*)(ws + A_CUR0); off = (int*)(ws + A_OFF0); N = N0; break;
        case 1:  cur = (int*)(ws + A_CUR1); off = (int*)(ws + A_OFF1); N = N1; break;
        case 2:  cur = (int*)(ws + A_CUR2); off = (int*)(ws + A_OFF2); N = N2; break;
        default: cur = (int*)(ws + A_CUR3); off = (int*)(ws + A_OFF3); N = N3; break;
    }
    int t = threadIdx.x;
    int chunk = (N + 1023) >> 10;
    int b0 = t * chunk;
    int b1 = min(b0 + chunk, N);
    int s = 0;
    for (int i = b0; i < b1; ++i) s += cur[i];
    ls[t] = s;
    __syncthreads();
    for (int d = 1; d < 1024; d <<= 1) {
        int v = (t >= d) ? ls[t - d] : 0;
        __syncthreads();
        ls[t] += v;
        __syncthreads();
    }
    int run = (t == 0) ? 0 : ls[t - 1];
    for (int i = b0; i < b1; ++i) {
        int c = cur[i];
        off[i] = run;
        cur[i] = run;   // cursor for scatter
        run += c;
    }
    if (t == 1023) off[N] = run;
}

// ---------------- P4: csr scatter + W transpose/cast (fused) ----------------
__global__ void prologue4(const int* __restrict__ d0, const int* __restrict__ d1,
                          const int* __restrict__ d2, const int* __restrict__ d3,
                          const float* __restrict__ W2, const float* __restrict__ W3,
                          const float* __restrict__ W4, float* __restrict__ ws) {
    __shared__ float st[64 * 129];
    int bid = blockIdx.x;
    int tid = threadIdx.x;
    if (bid < 3 * K3) {
        const float* W; unsigned short* wt; int IN, OUT, k;
        if (bid < K3)          { W = W2; wt = (unsigned short*)(ws + A_WT2); IN = 32; OUT = 64;  k = bid; }
        else if (bid < 2 * K3) { W = W3; wt = (unsigned short*)(ws + A_WT3); IN = 64; OUT = 64;  k = bid - K3; }
        else                   { W = W4; wt = (unsigned short*)(ws + A_WT4); IN = 64; OUT = 128; k = bid - 2 * K3; }
        int tot = IN * OUT;
        const float* Wk = W + (size_t)k * tot;
        for (int idx = tid; idx < tot; idx += 256) {
            int i = idx / OUT, o = idx % OUT;
            st[i * (OUT + 1) + o] = Wk[idx];
        }
        __syncthreads();
        unsigned short* wk = wt + (size_t)k * tot;
        for (int idx = tid; idx < tot; idx += 256) {
            int o = idx / IN, i = idx % IN;
            wk[idx] = f2bf(st[i * (OUT + 1) + o]);
        }
    } else {
        int g = (bid - 3 * K3) * 256 + tid;
        if (g < E0)                { int p = atomicAdd((int*)(ws + A_CUR0) + d0[g], 1);            ((int*)(ws + A_EIX0))[p] = g; }
        else if (g < E0 + E1)      { int e = g - E0;           int p = atomicAdd((int*)(ws + A_CUR1) + d1[e], 1); ((int*)(ws + A_EIX1))[p] = e; }
        else if (g < E0 + E1 + E2) { int e = g - E0 - E1;      int p = atomicAdd((int*)(ws + A_CUR2) + d2[e], 1); ((int*)(ws + A_EIX2))[p] = e; }
        else if (g < E_TOT)        { int e = g - E0 - E1 - E2; int p = atomicAdd((int*)(ws + A_CUR3) + d3[e], 1); ((int*)(ws + A_EIX3))[p] = e; }
    }
}

// ---------------- layer 1: half-wave per node, W1 in LDS, 2-edge unrolled ----------
__global__ __launch_bounds__(256) void l1_agg(const float* __restrict__ x0,
                                              const float* __restrict__ bas,
                                              const u64* __restrict__ kid,
                                              const int* __restrict__ src,
                                              const int* __restrict__ off,
                                              const int* __restrict__ eidx,
                                              const float* __restrict__ W1,
                                              const float* __restrict__ root1,
                                              const float* __restrict__ b1,
                                              const int* __restrict__ cl,
                                              unsigned* __restrict__ penc) {
    __shared__ float wlds[K3 * 32];
    int tid = threadIdx.x;
    for (int i = tid; i < K3 * 32; i += 256) wlds[i] = W1[i];
    __syncthreads();
    int o = tid & 31;
    int nsub = tid >> 5;
    int n = blockIdx.x * 8 + nsub;
    int s0 = off[n], s1 = off[n + 1];
    float acc = 0.f;
    int j = s0;
    for (; j + 2 <= s1; j += 2) {
        int ea = eidx[j], eb = eidx[j + 1];
        float4 qa0 = *(const float4*)(bas + (size_t)ea * 8);
        float4 qa1 = *(const float4*)(bas + (size_t)ea * 8 + 4);
        float4 qb0 = *(const float4*)(bas + (size_t)eb * 8);
        float4 qb1 = *(const float4*)(bas + (size_t)eb * 8 + 4);
        u64 ka = kid[ea], kb = kid[eb];
        float xa = x0[src[ea]], xb = x0[src[eb]];
        float ma, mb;
        ma  = qa0.x * wlds[((int)( ka        & 255u)) * 32 + o];
        ma += qa0.y * wlds[((int)((ka >>  8) & 255u)) * 32 + o];
        ma += qa0.z * wlds[((int)((ka >> 16) & 255u)) * 32 + o];
        ma += qa0.w * wlds[((int)((ka >> 24) & 255u)) * 32 + o];
        ma += qa1.x * wlds[((int)((ka >> 32) & 255u)) * 32 + o];
        ma += qa1.y * wlds[((int)((ka >> 40) & 255u)) * 32 + o];
        ma += qa1.z * wlds[((int)((ka >> 48) & 255u)) * 32 + o];
        ma += qa1.w * wlds[((int)((ka >> 56) & 255u)) * 32 + o];
        mb  = qb0.x * wlds[((int)( kb        & 255u)) * 32 + o];
        mb += qb0.y * wlds[((int)((kb >>  8) & 255u)) * 32 + o];
        mb += qb0.z * wlds[((int)((kb >> 16) & 255u)) * 32 + o];
        mb += qb0.w * wlds[((int)((kb >> 24) & 255u)) * 32 + o];
        mb += qb1.x * wlds[((int)((kb >> 32) & 255u)) * 32 + o];
        mb += qb1.y * wlds[((int)((kb >> 40) & 255u)) * 32 + o];
        mb += qb1.z * wlds[((int)((kb >> 48) & 255u)) * 32 + o];
        mb += qb1.w * wlds[((int)((kb >> 56) & 255u)) * 32 + o];
        acc = fmaf(xa, ma, fmaf(xb, mb, acc));
    }
    if (j < s1) {
        int e = eidx[j];
        float4 q0 = *(const float4*)(bas + (size_t)e * 8);
        float4 q1 = *(const float4*)(bas + (size_t)e * 8 + 4);
        u64 k8 = kid[e];
        float xv = x0[src[e]];
        float m;
        m  = q0.x * wlds[((int)( k8        & 255u)) * 32 + o];
        m += q0.y * wlds[((int)((k8 >>  8) & 255u)) * 32 + o];
        m += q0.z * wlds[((int)((k8 >> 16) & 255u)) * 32 + o];
        m += q0.w * wlds[((int)((k8 >> 24) & 255u)) * 32 + o];
        m += q1.x * wlds[((int)((k8 >> 32) & 255u)) * 32 + o];
        m += q1.y * wlds[((int)((k8 >> 40) & 255u)) * 32 + o];
        m += q1.z * wlds[((int)((k8 >> 48) & 255u)) * 32 + o];
        m += q1.w * wlds[((int)((k8 >> 56) & 255u)) * 32 + o];
        acc = fmaf(xv, m, acc);
    }
    float dg = fmaxf((float)(s1 - s0), 1.f);
    float val = acc / dg + x0[n] * root1[o] + b1[o];
    val = eluf(val);
    atomicMax(&penc[(size_t)cl[n] * 32 + o], enc_f(val));
}

// ---------------- MFMA y = x @ W, x decoded inline from encoded pool buffer ------
template <int IN>
__global__ __launch_bounds__(256) void gemm_y_mfma(const unsigned* __restrict__ penc,
                                                   const unsigned short* __restrict__ wt,
                                                   unsigned short* __restrict__ y,
                                                   int N, int KO) {
    int wid = (blockIdx.x * 256 + threadIdx.x) >> 6;
    int lane = threadIdx.x & 63;
    int nTiles = N >> 4;
    int n0 = (wid % nTiles) << 4;
    int ko0 = (wid / nTiles) << 6;
    int l15 = lane & 15;
    int kk = (lane >> 4) << 3;

    f32x4 acc[4];
#pragma unroll
    for (int t = 0; t < 4; ++t) acc[t] = (f32x4){0.f, 0.f, 0.f, 0.f};

#pragma unroll
    for (int s = 0; s < IN / 32; ++s) {
        const unsigned* pp = penc + (size_t)(n0 + l15) * IN + s * 32 + kk;
        uint4 u0 = *(const uint4*)pp;
        uint4 u1 = *(const uint4*)(pp + 4);
        unsigned uu[8] = {u0.x, u0.y, u0.z, u0.w, u1.x, u1.y, u1.z, u1.w};
        bf16x8 bfrag;
#pragma unroll
        for (int t = 0; t < 8; ++t) bfrag[t] = (short)f2bf(dec_fin(uu[t]));
#pragma unroll
        for (int t = 0; t < 4; ++t) {
            bf16x8 afrag = *(const bf16x8*)(wt + (size_t)(ko0 + t * 16 + l15) * IN + s * 32 + kk);
            acc[t] = __builtin_amdgcn_mfma_f32_16x16x32_bf16(afrag, bfrag, acc[t], 0, 0, 0);
        }
    }
    int rbase = (lane >> 4) << 2;
#pragma unroll
    for (int t = 0; t < 4; ++t) {
        ushort4 sv;
        sv.x = f2bf(acc[t][0]);
        sv.y = f2bf(acc[t][1]);
        sv.z = f2bf(acc[t][2]);
        sv.w = f2bf(acc[t][3]);
        *(ushort4*)(y + (size_t)(n0 + l15) * KO + ko0 + t * 16 + rbase) = sv;
    }
}

// ---------------- layers 2-4: wave-per-node gather+agg+finish+pool, 2-edge unroll --
template <int IN, int OUT>
__global__ __launch_bounds__(256) void gather_agg(const unsigned short* __restrict__ y,
                                                  const float* __restrict__ bas,
                                                  const u64* __restrict__ kid,
                                                  const int* __restrict__ src,
                                                  const int* __restrict__ off,
                                                  const int* __restrict__ eidx,
                                                  const unsigned* __restrict__ penc_prev,
                                                  const float* __restrict__ root,
                                                  const float* __restrict__ bias,
                                                  const int* __restrict__ cl,
                                                  unsigned* __restrict__ penc) {
    constexpr int KO = K3 * OUT;
    constexpr int WPT = OUT / 64;
    int lane = threadIdx.x & 63;
    int wv = threadIdx.x >> 6;
    int n = blockIdx.x * 4 + wv;
    int s0 = off[n], s1 = off[n + 1];
    float acc0 = 0.f, acc1 = 0.f;
    int j = s0;
    for (; j + 2 <= s1; j += 2) {
        int ea = eidx[j], eb = eidx[j + 1];
        float4 qa0 = *(const float4*)(bas + (size_t)ea * 8);
        float4 qa1 = *(const float4*)(bas + (size_t)ea * 8 + 4);
        float4 qb0 = *(const float4*)(bas + (size_t)eb * 8);
        float4 qb1 = *(const float4*)(bas + (size_t)eb * 8 + 4);
        u64 ka = kid[ea], kb = kid[eb];
        const unsigned short* ypa = y + (size_t)src[ea] * KO + lane;
        const unsigned short* ypb = y + (size_t)src[eb] * KO + lane;
        float ba[8] = {qa0.x, qa0.y, qa0.z, qa0.w, qa1.x, qa1.y, qa1.z, qa1.w};
        float bb[8] = {qb0.x, qb0.y, qb0.z, qb0.w, qb1.x, qb1.y, qb1.z, qb1.w};
        float va[8], vb[8], va2[8], vb2[8];
#pragma unroll
        for (int c = 0; c < 8; ++c) {
            int kca = (int)((ka >> (8 * c)) & 255u);
            int kcb = (int)((kb >> (8 * c)) & 255u);
            va[c] = bf2f(ypa[(size_t)kca * OUT]);
            vb[c] = bf2f(ypb[(size_t)kcb * OUT]);
            if (WPT == 2) {
                va2[c] = bf2f(ypa[(size_t)kca * OUT + 64]);
                vb2[c] = bf2f(ypb[(size_t)kcb * OUT + 64]);
            }
        }
#pragma unroll
        for (int c = 0; c < 8; ++c) {
            acc0 = fmaf(ba[c], va[c], acc0);
            acc0 = fmaf(bb[c], vb[c], acc0);
            if (WPT == 2) {
                acc1 = fmaf(ba[c], va2[c], acc1);
                acc1 = fmaf(bb[c], vb2[c], acc1);
            }
        }
    }
    if (j < s1) {
        int e = eidx[j];
        float4 q0 = *(const float4*)(bas + (size_t)e * 8);
        float4 q1 = *(const float4*)(bas + (size_t)e * 8 + 4);
        u64 k8 = kid[e];
        const unsigned short* yp = y + (size_t)src[e] * KO + lane;
        float b[8] = {q0.x, q0.y, q0.z, q0.w, q1.x, q1.y, q1.z, q1.w};
#pragma unroll
        for (int c = 0; c < 8; ++c) {
            int kc = (int)((k8 >> (8 * c)) & 255u);
            acc0 = fmaf(b[c], bf2f(yp[(size_t)kc * OUT]), acc0);
            if (WPT == 2) acc1 = fmaf(b[c], bf2f(yp[(size_t)kc * OUT + 64]), acc1);
        }
    }
    float dg = fmaxf((float)(s1 - s0), 1.f);
    float accs[2] = {acc0, acc1};
#pragma unroll
    for (int w = 0; w < WPT; ++w) {
        int o = lane + 64 * w;
        float r = 0.f;
        for (int i = 0; i < IN; ++i)
            r = fmaf(dec_fin(penc_prev[(size_t)n * IN + i]), root[(size_t)i * OUT + o], r);
        float val = accs[w] / dg + r + bias[o];
        val = eluf(val);
        atomicMax(&penc[(size_t)cl[n] * OUT + o], enc_f(val));
    }
}

// ---------------- FC head: fc1 + ELU + fc2 + log_softmax, one block per batch row --
__global__ __launch_bounds__(256) void fc_head(const unsigned* __restrict__ penc4,
                                               const float* __restrict__ w1,
                                               const float* __restrict__ b1,
                                               const float* __restrict__ w2,
                                               const float* __restrict__ b2,
                                               float* __restrict__ out) {
    __shared__ float xr[1024];
    __shared__ float h[256];
    __shared__ float l[10];
    __shared__ float red[2];
    int bq = blockIdx.x;
    int t = threadIdx.x;
    for (int idx = t; idx < 1024; idx += 256)
        xr[idx] = dec_fin(penc4[(size_t)bq * 1024 + idx]);
    __syncthreads();
    float acc = b1[t];
#pragma unroll 4
    for (int q = 0; q < 1024; ++q)
        acc = fmaf(xr[q], w1[(size_t)q * 256 + t], acc);
    h[t] = eluf(acc);
    __syncthreads();
    if (t < 10) {
        float a2 = b2[t];
        for (int q = 0; q < 256; ++q)
            a2 = fmaf(h[q], w2[(size_t)q * 10 + t], a2);
        l[t] = a2;
    }
    __syncthreads();
    if (t == 0) {
        float m = l[0];
        for (int i = 1; i < 10; ++i) m = fmaxf(m, l[i]);
        float s = 0.f;
        for (int i = 0; i < 10; ++i) s += expf(l[i] - m);
        red[0] = m;
        red[1] = logf(s);
    }
    __syncthreads();
    if (t < 10) out[(size_t)bq * 10 + t] = l[t] - red[0] - red[1];
}

inline unsigned blk(long long t) { return (unsigned)((t + 255) / 256); }

} // namespace

extern "C" void kernel_launch(void* const* d_in, const int* in_sizes, int n_in,
                              void* d_out, int out_size, void* d_ws, size_t ws_size,
                              hipStream_t stream) {
    const float* x0    = (const float*)d_in[0];
    const float* ps0   = (const float*)d_in[1];
    const float* ps1   = (const float*)d_in[2];
    const float* ps2   = (const float*)d_in[3];
    const float* ps3   = (const float*)d_in[4];
    const float* W1    = (const float*)d_in[5];
    const float* root1 = (const float*)d_in[6];
    const float* b1    = (const float*)d_in[7];
    const float* W2    = (const float*)d_in[8];
    const float* root2 = (const float*)d_in[9];
    const float* b2    = (const float*)d_in[10];
    const float* W3    = (const float*)d_in[11];
    const float* root3 = (const float*)d_in[12];
    const float* b3    = (const float*)d_in[13];
    const float* W4    = (const float*)d_in[14];
    const float* root4 = (const float*)d_in[15];
    const float* b4    = (const float*)d_in[16];
    const float* fc1w  = (const float*)d_in[17];
    const float* fc1b  = (const float*)d_in[18];
    const float* fc2w  = (const float*)d_in[19];
    const float* fc2b  = (const float*)d_in[20];
    const int* src0 = (const int*)d_in[21];
    const int* dst0 = (const int*)d_in[22];
    const int* src1 = (const int*)d_in[23];
    const int* dst1 = (const int*)d_in[24];
    const int* src2 = (const int*)d_in[25];
    const int* dst2 = (const int*)d_in[26];
    const int* src3 = (const int*)d_in[27];
    const int* dst3 = (const int*)d_in[28];
    const int* cl0  = (const int*)d_in[29];
    const int* cl1  = (const int*)d_in[30];
    const int* cl2  = (const int*)d_in[31];
    const int* cl3  = (const int*)d_in[32];

    float* ws = (float*)d_ws;
    float* out = (float*)d_out;

    unsigned* penc1 = (unsigned*)(ws + A_PENC1);
    unsigned* penc2 = (unsigned*)(ws + A_PENC2);
    unsigned* penc3 = (unsigned*)(ws + A_PENC3);
    unsigned* penc4 = (unsigned*)(ws + A_PENC4);
    unsigned short* wt2 = (unsigned short*)(ws + A_WT2);
    unsigned short* wt3 = (unsigned short*)(ws + A_WT3);
    unsigned short* wt4 = (unsigned short*)(ws + A_WT4);
    float* bas0 = ws + A_BAS0;  u64* kid0 = (u64*)(ws + A_KID0);
    float* bas1 = ws + A_BAS1;  u64* kid1 = (u64*)(ws + A_KID1);
    float* bas2 = ws + A_BAS2;  u64* kid2 = (u64*)(ws + A_KID2);
    float* bas3 = ws + A_BAS3;  u64* kid3 = (u64*)(ws + A_KID3);
    int* off0 = (int*)(ws + A_OFF0);  int* eix0 = (int*)(ws + A_EIX0);
    int* off1 = (int*)(ws + A_OFF1);  int* eix1 = (int*)(ws + A_EIX1);
    int* off2 = (int*)(ws + A_OFF2);  int* eix2 = (int*)(ws + A_EIX2);
    int* off3 = (int*)(ws + A_OFF3);  int* eix3 = (int*)(ws + A_EIX3);
    unsigned short* yb = (unsigned short*)(ws + A_Y);

    // ---- prologue: decode+init, hist, scan, scatter+Wt ----
    prologue1<<<blk(E_TOT), 256, 0, stream>>>(ps0, ps1, ps2, ps3, ws);
    csr_hist<<<blk(E_TOT), 256, 0, stream>>>(dst0, dst1, dst2, dst3, ws);
    csr_scan<<<4, 1024, 0, stream>>>(ws);
    prologue4<<<3 * K3 + blk(E_TOT), 256, 0, stream>>>(dst0, dst1, dst2, dst3, W2, W3, W4, ws);

    // ---- layer 1: conv(1->32) on N0, pool -> penc1 ----
    l1_agg<<<N0 / 8, 256, 0, stream>>>(x0, bas0, kid0, src0, off0, eix0, W1, root1, b1, cl0, penc1);

    // ---- layer 2: conv(32->64) on N1, pool -> penc2 ----
    gemm_y_mfma<32><<<(N1 / 16) * (K3 * 64 / 64) / 4, 256, 0, stream>>>(penc1, wt2, yb, N1, K3 * 64);
    gather_agg<32, 64><<<N1 / 4, 256, 0, stream>>>(yb, bas1, kid1, src1, off1, eix1,
                                                   penc1, root2, b2, cl1, penc2);

    // ---- layer 3: conv(64->64) on N2, pool -> penc3 ----
    gemm_y_mfma<64><<<(N2 / 16) * (K3 * 64 / 64) / 4, 256, 0, stream>>>(penc2, wt3, yb, N2, K3 * 64);
    gather_agg<64, 64><<<N2 / 4, 256, 0, stream>>>(yb, bas2, kid2, src2, off2, eix2,
                                                   penc2, root3, b3, cl2, penc3);

    // ---- layer 4: conv(64->128) on N3, pool -> penc4 ----
    gemm_y_mfma<64><<<(N3 / 16) * (K3 * 128 / 64) / 4, 256, 0, stream>>>(penc3, wt4, yb, N3, K3 * 128);
    gather_agg<64, 128><<<N3 / 4, 256, 0, stream>>>(yb, bas3, kid3, src3, off3, eix3,
                                                    penc3, root4, b4, cl3, penc4);

    // ---- FC head ----
    fc_head<<<16, 256, 0, stream>>>(penc4, fc1w, fc1b, fc2w, fc2b, out);
}

// Round 6
// 346.781 us; speedup vs baseline: 1.1753x; 1.1707x over previous
//
#include <hip/hip_runtime.h>
#include <hip/hip_bf16.h>
#include <math.h>

namespace {

typedef unsigned long long u64;
typedef __attribute__((ext_vector_type(8))) short bf16x8;
typedef __attribute__((ext_vector_type(4))) float f32x4;

constexpr int KK = 5;
constexpr int K3 = 125;
constexpr int N0 = 16384, E0 = 262144;
constexpr int N1 = 4096,  E1 = 65536;
constexpr int N2 = 1024,  E2 = 16384;
constexpr int N3 = 256,   E3 = 4096;
constexpr int NV = 128;
constexpr int E_TOT = E0 + E1 + E2 + E3;     // 348160
constexpr unsigned ENC_NEG_INF = 0x007FFFFFu;

// ---------------- workspace layout (float-slot offsets) ----------------
constexpr size_t A_PENC1 = 0;                              // N1*32
constexpr size_t A_PENC2 = A_PENC1 + (size_t)N1 * 32;      // N2*64
constexpr size_t A_PENC3 = A_PENC2 + (size_t)N2 * 64;      // N3*64
constexpr size_t A_PENC4 = A_PENC3 + (size_t)N3 * 64;      // NV*128
constexpr size_t A_PENC_END = A_PENC4 + (size_t)NV * 128;
constexpr size_t PENC_TOTAL = A_PENC_END;                  // 229376

constexpr size_t A_WT2 = A_PENC_END;                       // bf16: K3*64*32
constexpr size_t A_WT3 = A_WT2 + (size_t)K3 * 64 * 32 / 2;
constexpr size_t A_WT4 = A_WT3 + (size_t)K3 * 64 * 64 / 2;

constexpr size_t A_BAS0 = A_WT4 + (size_t)K3 * 128 * 64 / 2;
constexpr size_t A_KID0 = A_BAS0 + (size_t)E0 * 8;
constexpr size_t A_BAS1 = A_KID0 + (size_t)E0 * 2;
constexpr size_t A_KID1 = A_BAS1 + (size_t)E1 * 8;
constexpr size_t A_BAS2 = A_KID1 + (size_t)E1 * 2;
constexpr size_t A_KID2 = A_BAS2 + (size_t)E2 * 8;
constexpr size_t A_BAS3 = A_KID2 + (size_t)E2 * 2;
constexpr size_t A_KID3 = A_BAS3 + (size_t)E3 * 8;

constexpr size_t A_OFF0 = A_KID3 + (size_t)E3 * 2;
constexpr size_t A_OFF1 = A_OFF0 + (N0 + 4);
constexpr size_t A_OFF2 = A_OFF1 + (N1 + 4);
constexpr size_t A_OFF3 = A_OFF2 + (N2 + 4);
constexpr size_t A_CUR0 = A_OFF3 + (N3 + 4);
constexpr size_t A_CUR1 = A_CUR0 + N0;
constexpr size_t A_CUR2 = A_CUR1 + N1;
constexpr size_t A_CUR3 = A_CUR2 + N2;
constexpr size_t A_CUR_END = A_CUR3 + N3;
constexpr size_t CUR_TOTAL = A_CUR_END - A_CUR0;           // 21760
constexpr size_t A_EIX0 = A_CUR_END;
constexpr size_t A_EIX1 = A_EIX0 + E0;
constexpr size_t A_EIX2 = A_EIX1 + E1;
constexpr size_t A_EIX3 = A_EIX2 + E2;
constexpr size_t A_Y = A_EIX3 + E3;                        // bf16, max N1*8000
constexpr size_t Y_FLOATS = (size_t)N1 * (K3 * 64) / 2;
constexpr size_t A_FCP = A_Y + Y_FLOATS;                   // 16*16*256 partials

// ---------------- helpers ----------------
__device__ __forceinline__ float eluf(float x) { return x > 0.f ? x : expm1f(x); }

__device__ __forceinline__ unsigned enc_f(float x) {
    unsigned u = __float_as_uint(x);
    return (u & 0x80000000u) ? ~u : (u | 0x80000000u);
}
__device__ __forceinline__ float dec_fin(unsigned u) {   // decode + (-inf -> 0)
    u = (u & 0x80000000u) ? (u & 0x7fffffffu) : ~u;
    float v = __uint_as_float(u);
    return isfinite(v) ? v : 0.f;
}
__device__ __forceinline__ float bf2f(unsigned short u) {
    return __uint_as_float((unsigned)u << 16);
}
__device__ __forceinline__ unsigned short f2bf(float v) {
    __hip_bfloat16 h = __float2bfloat16(v);
    return *reinterpret_cast<unsigned short*>(&h);
}

__device__ __forceinline__ void decode_edge(const float* __restrict__ pseudo, int e,
                                            float bas[8], int kid[8]) {
    float v0 = pseudo[e * 3 + 0] * (KK - 1);
    float v1 = pseudo[e * 3 + 1] * (KK - 1);
    float v2 = pseudo[e * 3 + 2] * (KK - 1);
    float f0 = fminf(fmaxf(floorf(v0), 0.f), (float)(KK - 2));
    float f1 = fminf(fmaxf(floorf(v1), 0.f), (float)(KK - 2));
    float f2 = fminf(fmaxf(floorf(v2), 0.f), (float)(KK - 2));
    int lo0 = (int)f0, lo1 = (int)f1, lo2 = (int)f2;
    float fr0 = v0 - f0, fr1 = v1 - f1, fr2 = v2 - f2;
#pragma unroll
    for (int c = 0; c < 8; ++c) {
        int b0 = c & 1, b1 = (c >> 1) & 1, b2 = (c >> 2) & 1;
        kid[c] = (lo0 + b0) + (lo1 + b1) * KK + (lo2 + b2) * KK * KK;
        bas[c] = (b0 ? fr0 : 1.f - fr0) * (b1 ? fr1 : 1.f - fr1) * (b2 ? fr2 : 1.f - fr2);
    }
}

// ---------------- P1: decode all bases + init penc + dst histogram ----------------
// cursors are zeroed by hipMemsetAsync before this kernel
__global__ void prologue1(const float* __restrict__ ps0, const float* __restrict__ ps1,
                          const float* __restrict__ ps2, const float* __restrict__ ps3,
                          const int* __restrict__ d0, const int* __restrict__ d1,
                          const int* __restrict__ d2, const int* __restrict__ d3,
                          float* __restrict__ ws) {
    int g = blockIdx.x * blockDim.x + threadIdx.x;
    if (g < (int)PENC_TOTAL) ((unsigned*)(ws + A_PENC1))[g] = ENC_NEG_INF;
    if (g >= E_TOT) return;
    const float* ps; float* bas; u64* kid; int e; const int* dst; int* cur;
    if (g < E0)                { ps = ps0; bas = ws + A_BAS0; kid = (u64*)(ws + A_KID0); e = g;                dst = d0; cur = (int*)(ws + A_CUR0); }
    else if (g < E0 + E1)      { ps = ps1; bas = ws + A_BAS1; kid = (u64*)(ws + A_KID1); e = g - E0;           dst = d1; cur = (int*)(ws + A_CUR1); }
    else if (g < E0 + E1 + E2) { ps = ps2; bas = ws + A_BAS2; kid = (u64*)(ws + A_KID2); e = g - E0 - E1;      dst = d2; cur = (int*)(ws + A_CUR2); }
    else                       { ps = ps3; bas = ws + A_BAS3; kid = (u64*)(ws + A_KID3); e = g - E0 - E1 - E2; dst = d3; cur = (int*)(ws + A_CUR3); }
    atomicAdd(&cur[dst[e]], 1);
    float b[8]; int k[8];
    decode_edge(ps, e, b, k);
    *(float4*)(bas + (size_t)e * 8)     = make_float4(b[0], b[1], b[2], b[3]);
    *(float4*)(bas + (size_t)e * 8 + 4) = make_float4(b[4], b[5], b[6], b[7]);
    u64 p = 0;
#pragma unroll
    for (int c = 0; c < 8; ++c) p |= (u64)(unsigned)k[c] << (8 * c);
    kid[e] = p;
}

// ---------------- P3: exclusive scan per layer (4 blocks) ----------------
__global__ void csr_scan(float* __restrict__ ws) {
    __shared__ int ls[1024];
    int* cur; int* off; int N;
    switch (blockIdx.x) {
        case 0:  cur = (int*)(ws + A_CUR0); off = (int*)(ws + A_OFF0); N = N0; break;
        case 1:  cur = (int*)(ws + A_CUR1); off = (int*)(ws + A_OFF1); N = N1; break;
        case 2:  cur = (int*)(ws + A_CUR2); off = (int*)(ws + A_OFF2); N = N2; break;
        default: cur = (int*)(ws + A_CUR3); off = (int*)(ws + A_OFF3); N = N3; break;
    }
    int t = threadIdx.x;
    int chunk = (N + 1023) >> 10;
    int b0 = t * chunk;
    int b1 = min(b0 + chunk, N);
    int s = 0;
    for (int i = b0; i < b1; ++i) s += cur[i];
    ls[t] = s;
    __syncthreads();
    for (int d = 1; d < 1024; d <<= 1) {
        int v = (t >= d) ? ls[t - d] : 0;
        __syncthreads();
        ls[t] += v;
        __syncthreads();
    }
    int run = (t == 0) ? 0 : ls[t - 1];
    for (int i = b0; i < b1; ++i) {
        int c = cur[i];
        off[i] = run;
        cur[i] = run;   // cursor for scatter
        run += c;
    }
    if (t == 1023) off[N] = run;
}

// ---------------- P4: csr scatter + W transpose/cast (fused) ----------------
__global__ void prologue4(const int* __restrict__ d0, const int* __restrict__ d1,
                          const int* __restrict__ d2, const int* __restrict__ d3,
                          const float* __restrict__ W2, const float* __restrict__ W3,
                          const float* __restrict__ W4, float* __restrict__ ws) {
    __shared__ float st[64 * 129];
    int bid = blockIdx.x;
    int tid = threadIdx.x;
    if (bid < 3 * K3) {
        const float* W; unsigned short* wt; int IN, OUT, k;
        if (bid < K3)          { W = W2; wt = (unsigned short*)(ws + A_WT2); IN = 32; OUT = 64;  k = bid; }
        else if (bid < 2 * K3) { W = W3; wt = (unsigned short*)(ws + A_WT3); IN = 64; OUT = 64;  k = bid - K3; }
        else                   { W = W4; wt = (unsigned short*)(ws + A_WT4); IN = 64; OUT = 128; k = bid - 2 * K3; }
        int tot = IN * OUT;
        const float* Wk = W + (size_t)k * tot;
        for (int idx = tid; idx < tot; idx += 256) {
            int i = idx / OUT, o = idx % OUT;
            st[i * (OUT + 1) + o] = Wk[idx];
        }
        __syncthreads();
        unsigned short* wk = wt + (size_t)k * tot;
        for (int idx = tid; idx < tot; idx += 256) {
            int o = idx / IN, i = idx % IN;
            wk[idx] = f2bf(st[i * (OUT + 1) + o]);
        }
    } else {
        int g = (bid - 3 * K3) * 256 + tid;
        if (g < E0)                { int p = atomicAdd((int*)(ws + A_CUR0) + d0[g], 1);            ((int*)(ws + A_EIX0))[p] = g; }
        else if (g < E0 + E1)      { int e = g - E0;           int p = atomicAdd((int*)(ws + A_CUR1) + d1[e], 1); ((int*)(ws + A_EIX1))[p] = e; }
        else if (g < E0 + E1 + E2) { int e = g - E0 - E1;      int p = atomicAdd((int*)(ws + A_CUR2) + d2[e], 1); ((int*)(ws + A_EIX2))[p] = e; }
        else if (g < E_TOT)        { int e = g - E0 - E1 - E2; int p = atomicAdd((int*)(ws + A_CUR3) + d3[e], 1); ((int*)(ws + A_EIX3))[p] = e; }
    }
}

// ---------------- layer 1: half-wave per node, W1 in LDS, 2-edge unrolled ----------
__global__ __launch_bounds__(256) void l1_agg(const float* __restrict__ x0,
                                              const float* __restrict__ bas,
                                              const u64* __restrict__ kid,
                                              const int* __restrict__ src,
                                              const int* __restrict__ off,
                                              const int* __restrict__ eidx,
                                              const float* __restrict__ W1,
                                              const float* __restrict__ root1,
                                              const float* __restrict__ b1,
                                              const int* __restrict__ cl,
                                              unsigned* __restrict__ penc) {
    __shared__ float wlds[K3 * 32];
    int tid = threadIdx.x;
    for (int i = tid; i < K3 * 32; i += 256) wlds[i] = W1[i];
    __syncthreads();
    int o = tid & 31;
    int nsub = tid >> 5;
    int n = blockIdx.x * 8 + nsub;
    int s0 = off[n], s1 = off[n + 1];
    float acc = 0.f;
    int j = s0;
    for (; j + 2 <= s1; j += 2) {
        int ea = eidx[j], eb = eidx[j + 1];
        float4 qa0 = *(const float4*)(bas + (size_t)ea * 8);
        float4 qa1 = *(const float4*)(bas + (size_t)ea * 8 + 4);
        float4 qb0 = *(const float4*)(bas + (size_t)eb * 8);
        float4 qb1 = *(const float4*)(bas + (size_t)eb * 8 + 4);
        u64 ka = kid[ea], kb = kid[eb];
        float xa = x0[src[ea]], xb = x0[src[eb]];
        float ma, mb;
        ma  = qa0.x * wlds[((int)( ka        & 255u)) * 32 + o];
        ma += qa0.y * wlds[((int)((ka >>  8) & 255u)) * 32 + o];
        ma += qa0.z * wlds[((int)((ka >> 16) & 255u)) * 32 + o];
        ma += qa0.w * wlds[((int)((ka >> 24) & 255u)) * 32 + o];
        ma += qa1.x * wlds[((int)((ka >> 32) & 255u)) * 32 + o];
        ma += qa1.y * wlds[((int)((ka >> 40) & 255u)) * 32 + o];
        ma += qa1.z * wlds[((int)((ka >> 48) & 255u)) * 32 + o];
        ma += qa1.w * wlds[((int)((ka >> 56) & 255u)) * 32 + o];
        mb  = qb0.x * wlds[((int)( kb        & 255u)) * 32 + o];
        mb += qb0.y * wlds[((int)((kb >>  8) & 255u)) * 32 + o];
        mb += qb0.z * wlds[((int)((kb >> 16) & 255u)) * 32 + o];
        mb += qb0.w * wlds[((int)((kb >> 24) & 255u)) * 32 + o];
        mb += qb1.x * wlds[((int)((kb >> 32) & 255u)) * 32 + o];
        mb += qb1.y * wlds[((int)((kb >> 40) & 255u)) * 32 + o];
        mb += qb1.z * wlds[((int)((kb >> 48) & 255u)) * 32 + o];
        mb += qb1.w * wlds[((int)((kb >> 56) & 255u)) * 32 + o];
        acc = fmaf(xa, ma, fmaf(xb, mb, acc));
    }
    if (j < s1) {
        int e = eidx[j];
        float4 q0 = *(const float4*)(bas + (size_t)e * 8);
        float4 q1 = *(const float4*)(bas + (size_t)e * 8 + 4);
        u64 k8 = kid[e];
        float xv = x0[src[e]];
        float m;
        m  = q0.x * wlds[((int)( k8        & 255u)) * 32 + o];
        m += q0.y * wlds[((int)((k8 >>  8) & 255u)) * 32 + o];
        m += q0.z * wlds[((int)((k8 >> 16) & 255u)) * 32 + o];
        m += q0.w * wlds[((int)((k8 >> 24) & 255u)) * 32 + o];
        m += q1.x * wlds[((int)((k8 >> 32) & 255u)) * 32 + o];
        m += q1.y * wlds[((int)((k8 >> 40) & 255u)) * 32 + o];
        m += q1.z * wlds[((int)((k8 >> 48) & 255u)) * 32 + o];
        m += q1.w * wlds[((int)((k8 >> 56) & 255u)) * 32 + o];
        acc = fmaf(xv, m, acc);
    }
    float dg = fmaxf((float)(s1 - s0), 1.f);
    float val = acc / dg + x0[n] * root1[o] + b1[o];
    val = eluf(val);
    atomicMax(&penc[(size_t)cl[n] * 32 + o], enc_f(val));
}

// ---------------- MFMA y = x @ W, x decoded inline from encoded pool buffer ------
template <int IN>
__global__ __launch_bounds__(256) void gemm_y_mfma(const unsigned* __restrict__ penc,
                                                   const unsigned short* __restrict__ wt,
                                                   unsigned short* __restrict__ y,
                                                   int N, int KO) {
    int wid = (blockIdx.x * 256 + threadIdx.x) >> 6;
    int lane = threadIdx.x & 63;
    int nTiles = N >> 4;
    int n0 = (wid % nTiles) << 4;
    int ko0 = (wid / nTiles) << 6;
    int l15 = lane & 15;
    int kk = (lane >> 4) << 3;

    f32x4 acc[4];
#pragma unroll
    for (int t = 0; t < 4; ++t) acc[t] = (f32x4){0.f, 0.f, 0.f, 0.f};

#pragma unroll
    for (int s = 0; s < IN / 32; ++s) {
        const unsigned* pp = penc + (size_t)(n0 + l15) * IN + s * 32 + kk;
        uint4 u0 = *(const uint4*)pp;
        uint4 u1 = *(const uint4*)(pp + 4);
        unsigned uu[8] = {u0.x, u0.y, u0.z, u0.w, u1.x, u1.y, u1.z, u1.w};
        bf16x8 bfrag;
#pragma unroll
        for (int t = 0; t < 8; ++t) bfrag[t] = (short)f2bf(dec_fin(uu[t]));
#pragma unroll
        for (int t = 0; t < 4; ++t) {
            bf16x8 afrag = *(const bf16x8*)(wt + (size_t)(ko0 + t * 16 + l15) * IN + s * 32 + kk);
            acc[t] = __builtin_amdgcn_mfma_f32_16x16x32_bf16(afrag, bfrag, acc[t], 0, 0, 0);
        }
    }
    int rbase = (lane >> 4) << 2;
#pragma unroll
    for (int t = 0; t < 4; ++t) {
        ushort4 sv;
        sv.x = f2bf(acc[t][0]);
        sv.y = f2bf(acc[t][1]);
        sv.z = f2bf(acc[t][2]);
        sv.w = f2bf(acc[t][3]);
        *(ushort4*)(y + (size_t)(n0 + l15) * KO + ko0 + t * 16 + rbase) = sv;
    }
}

// ---------------- layers 2-4: wave-per-node gather+agg+finish+pool, 2-edge unroll --
template <int IN, int OUT>
__global__ __launch_bounds__(256) void gather_agg(const unsigned short* __restrict__ y,
                                                  const float* __restrict__ bas,
                                                  const u64* __restrict__ kid,
                                                  const int* __restrict__ src,
                                                  const int* __restrict__ off,
                                                  const int* __restrict__ eidx,
                                                  const unsigned* __restrict__ penc_prev,
                                                  const float* __restrict__ root,
                                                  const float* __restrict__ bias,
                                                  const int* __restrict__ cl,
                                                  unsigned* __restrict__ penc) {
    constexpr int KO = K3 * OUT;
    constexpr int WPT = OUT / 64;
    int lane = threadIdx.x & 63;
    int wv = threadIdx.x >> 6;
    int n = blockIdx.x * 4 + wv;
    int s0 = off[n], s1 = off[n + 1];
    float acc0 = 0.f, acc1 = 0.f;
    int j = s0;
    for (; j + 2 <= s1; j += 2) {
        int ea = eidx[j], eb = eidx[j + 1];
        float4 qa0 = *(const float4*)(bas + (size_t)ea * 8);
        float4 qa1 = *(const float4*)(bas + (size_t)ea * 8 + 4);
        float4 qb0 = *(const float4*)(bas + (size_t)eb * 8);
        float4 qb1 = *(const float4*)(bas + (size_t)eb * 8 + 4);
        u64 ka = kid[ea], kb = kid[eb];
        const unsigned short* ypa = y + (size_t)src[ea] * KO + lane;
        const unsigned short* ypb = y + (size_t)src[eb] * KO + lane;
        float ba[8] = {qa0.x, qa0.y, qa0.z, qa0.w, qa1.x, qa1.y, qa1.z, qa1.w};
        float bb[8] = {qb0.x, qb0.y, qb0.z, qb0.w, qb1.x, qb1.y, qb1.z, qb1.w};
        float va[8], vb[8], va2[8], vb2[8];
#pragma unroll
        for (int c = 0; c < 8; ++c) {
            int kca = (int)((ka >> (8 * c)) & 255u);
            int kcb = (int)((kb >> (8 * c)) & 255u);
            va[c] = bf2f(ypa[(size_t)kca * OUT]);
            vb[c] = bf2f(ypb[(size_t)kcb * OUT]);
            if (WPT == 2) {
                va2[c] = bf2f(ypa[(size_t)kca * OUT + 64]);
                vb2[c] = bf2f(ypb[(size_t)kcb * OUT + 64]);
            }
        }
#pragma unroll
        for (int c = 0; c < 8; ++c) {
            acc0 = fmaf(ba[c], va[c], acc0);
            acc0 = fmaf(bb[c], vb[c], acc0);
            if (WPT == 2) {
                acc1 = fmaf(ba[c], va2[c], acc1);
                acc1 = fmaf(bb[c], vb2[c], acc1);
            }
        }
    }
    if (j < s1) {
        int e = eidx[j];
        float4 q0 = *(const float4*)(bas + (size_t)e * 8);
        float4 q1 = *(const float4*)(bas + (size_t)e * 8 + 4);
        u64 k8 = kid[e];
        const unsigned short* yp = y + (size_t)src[e] * KO + lane;
        float b[8] = {q0.x, q0.y, q0.z, q0.w, q1.x, q1.y, q1.z, q1.w};
#pragma unroll
        for (int c = 0; c < 8; ++c) {
            int kc = (int)((k8 >> (8 * c)) & 255u);
            acc0 = fmaf(b[c], bf2f(yp[(size_t)kc * OUT]), acc0);
            if (WPT == 2) acc1 = fmaf(b[c], bf2f(yp[(size_t)kc * OUT + 64]), acc1);
        }
    }
    float dg = fmaxf((float)(s1 - s0), 1.f);
    float accs[2] = {acc0, acc1};
#pragma unroll
    for (int w = 0; w < WPT; ++w) {
        int o = lane + 64 * w;
        float r = 0.f;
        for (int i = 0; i < IN; ++i)
            r = fmaf(dec_fin(penc_prev[(size_t)n * IN + i]), root[(size_t)i * OUT + o], r);
        float val = accs[w] / dg + r + bias[o];
        val = eluf(val);
        atomicMax(&penc[(size_t)cl[n] * OUT + o], enc_f(val));
    }
}

// ---------------- FC1 partial: grid = 16 bq x 16 kslices, 256 threads = outputs ----
__global__ __launch_bounds__(256) void fc1_part(const unsigned* __restrict__ penc4,
                                                const float* __restrict__ w1,
                                                float* __restrict__ part) {
    __shared__ float xs[64];
    int ks = blockIdx.x & 15;
    int bq = blockIdx.x >> 4;
    int t = threadIdx.x;
    int k0 = ks * 64;
    if (t < 64) xs[t] = dec_fin(penc4[(size_t)bq * 1024 + k0 + t]);
    __syncthreads();
    const float* wp = w1 + (size_t)k0 * 256 + t;
    float acc = 0.f;
#pragma unroll 8
    for (int k = 0; k < 64; ++k)
        acc = fmaf(xs[k], wp[(size_t)k * 256], acc);
    part[((size_t)bq * 16 + ks) * 256 + t] = acc;
}

// ---------------- FC head: reduce partials + bias + ELU + fc2 + log_softmax ------
__global__ __launch_bounds__(256) void fc_head2(const float* __restrict__ part,
                                                const float* __restrict__ b1,
                                                const float* __restrict__ w2,
                                                const float* __restrict__ b2,
                                                float* __restrict__ out) {
    __shared__ float h[256];
    __shared__ float l[10];
    __shared__ float red[2];
    int bq = blockIdx.x;
    int t = threadIdx.x;
    const float* pp = part + (size_t)bq * 16 * 256 + t;
    float acc = b1[t];
#pragma unroll
    for (int ks = 0; ks < 16; ++ks) acc += pp[ks * 256];
    h[t] = eluf(acc);
    __syncthreads();
    if (t < 10) {
        float a2 = b2[t];
        for (int q = 0; q < 256; ++q)
            a2 = fmaf(h[q], w2[(size_t)q * 10 + t], a2);
        l[t] = a2;
    }
    __syncthreads();
    if (t == 0) {
        float m = l[0];
        for (int i = 1; i < 10; ++i) m = fmaxf(m, l[i]);
        float s = 0.f;
        for (int i = 0; i < 10; ++i) s += expf(l[i] - m);
        red[0] = m;
        red[1] = logf(s);
    }
    __syncthreads();
    if (t < 10) out[(size_t)bq * 10 + t] = l[t] - red[0] - red[1];
}

inline unsigned blk(long long t) { return (unsigned)((t + 255) / 256); }

} // namespace

extern "C" void kernel_launch(void* const* d_in, const int* in_sizes, int n_in,
                              void* d_out, int out_size, void* d_ws, size_t ws_size,
                              hipStream_t stream) {
    const float* x0    = (const float*)d_in[0];
    const float* ps0   = (const float*)d_in[1];
    const float* ps1   = (const float*)d_in[2];
    const float* ps2   = (const float*)d_in[3];
    const float* ps3   = (const float*)d_in[4];
    const float* W1    = (const float*)d_in[5];
    const float* root1 = (const float*)d_in[6];
    const float* b1    = (const float*)d_in[7];
    const float* W2    = (const float*)d_in[8];
    const float* root2 = (const float*)d_in[9];
    const float* b2    = (const float*)d_in[10];
    const float* W3    = (const float*)d_in[11];
    const float* root3 = (const float*)d_in[12];
    const float* b3    = (const float*)d_in[13];
    const float* W4    = (const float*)d_in[14];
    const float* root4 = (const float*)d_in[15];
    const float* b4    = (const float*)d_in[16];
    const float* fc1w  = (const float*)d_in[17];
    const float* fc1b  = (const float*)d_in[18];
    const float* fc2w  = (const float*)d_in[19];
    const float* fc2b  = (const float*)d_in[20];
    const int* src0 = (const int*)d_in[21];
    const int* dst0 = (const int*)d_in[22];
    const int* src1 = (const int*)d_in[23];
    const int* dst1 = (const int*)d_in[24];
    const int* src2 = (const int*)d_in[25];
    const int* dst2 = (const int*)d_in[26];
    const int* src3 = (const int*)d_in[27];
    const int* dst3 = (const int*)d_in[28];
    const int* cl0  = (const int*)d_in[29];
    const int* cl1  = (const int*)d_in[30];
    const int* cl2  = (const int*)d_in[31];
    const int* cl3  = (const int*)d_in[32];

    float* ws = (float*)d_ws;
    float* out = (float*)d_out;

    unsigned* penc1 = (unsigned*)(ws + A_PENC1);
    unsigned* penc2 = (unsigned*)(ws + A_PENC2);
    unsigned* penc3 = (unsigned*)(ws + A_PENC3);
    unsigned* penc4 = (unsigned*)(ws + A_PENC4);
    unsigned short* wt2 = (unsigned short*)(ws + A_WT2);
    unsigned short* wt3 = (unsigned short*)(ws + A_WT3);
    unsigned short* wt4 = (unsigned short*)(ws + A_WT4);
    float* bas0 = ws + A_BAS0;  u64* kid0 = (u64*)(ws + A_KID0);
    float* bas1 = ws + A_BAS1;  u64* kid1 = (u64*)(ws + A_KID1);
    float* bas2 = ws + A_BAS2;  u64* kid2 = (u64*)(ws + A_KID2);
    float* bas3 = ws + A_BAS3;  u64* kid3 = (u64*)(ws + A_KID3);
    int* off0 = (int*)(ws + A_OFF0);  int* eix0 = (int*)(ws + A_EIX0);
    int* off1 = (int*)(ws + A_OFF1);  int* eix1 = (int*)(ws + A_EIX1);
    int* off2 = (int*)(ws + A_OFF2);  int* eix2 = (int*)(ws + A_EIX2);
    int* off3 = (int*)(ws + A_OFF3);  int* eix3 = (int*)(ws + A_EIX3);
    unsigned short* yb = (unsigned short*)(ws + A_Y);
    float* fcp = ws + A_FCP;

    // ---- prologue: zero cursors, decode+init+hist, scan, scatter+Wt ----
    hipMemsetAsync(ws + A_CUR0, 0, CUR_TOTAL * sizeof(int), stream);
    prologue1<<<blk(E_TOT), 256, 0, stream>>>(ps0, ps1, ps2, ps3, dst0, dst1, dst2, dst3, ws);
    csr_scan<<<4, 1024, 0, stream>>>(ws);
    prologue4<<<3 * K3 + blk(E_TOT), 256, 0, stream>>>(dst0, dst1, dst2, dst3, W2, W3, W4, ws);

    // ---- layer 1: conv(1->32) on N0, pool -> penc1 ----
    l1_agg<<<N0 / 8, 256, 0, stream>>>(x0, bas0, kid0, src0, off0, eix0, W1, root1, b1, cl0, penc1);

    // ---- layer 2: conv(32->64) on N1, pool -> penc2 ----
    gemm_y_mfma<32><<<(N1 / 16) * (K3 * 64 / 64) / 4, 256, 0, stream>>>(penc1, wt2, yb, N1, K3 * 64);
    gather_agg<32, 64><<<N1 / 4, 256, 0, stream>>>(yb, bas1, kid1, src1, off1, eix1,
                                                   penc1, root2, b2, cl1, penc2);

    // ---- layer 3: conv(64->64) on N2, pool -> penc3 ----
    gemm_y_mfma<64><<<(N2 / 16) * (K3 * 64 / 64) / 4, 256, 0, stream>>>(penc2, wt3, yb, N2, K3 * 64);
    gather_agg<64, 64><<<N2 / 4, 256, 0, stream>>>(yb, bas2, kid2, src2, off2, eix2,
                                                   penc2, root3, b3, cl2, penc3);

    // ---- layer 4: conv(64->128) on N3, pool -> penc4 ----
    gemm_y_mfma<64><<<(N3 / 16) * (K3 * 128 / 64) / 4, 256, 0, stream>>>(penc3, wt4, yb, N3, K3 * 128);
    gather_agg<64, 128><<<N3 / 4, 256, 0, stream>>>(yb, bas3, kid3, src3, off3, eix3,
                                                    penc3, root4, b4, cl3, penc4);

    // ---- FC head: parallel fc1 partials + reduce/fc2/log_softmax ----
    fc1_part<<<16 * 16, 256, 0, stream>>>(penc4, fc1w, fcp);
    fc_head2<<<16, 256, 0, stream>>>(fcp, fc1b, fc2w, fc2b, out);
}